// Round 4
// baseline (3266.709 us; speedup 1.0000x reference)
//
#include <hip/hip_runtime.h>
#include <hip/hip_bf16.h>

// LSTM B=64, T=256, ID=512, HD=1024. Gates F,I,A,O.
// Round 8: Wh A-tile moved to LDS (register pinning failed twice: "+v" r6,
// "+a" r7 both left VGPR_Count at ~160, i.e. regalloc refuses 256 live regs
// across the t-loop and re-fetches Wh from L2 every step — the exposed
// latency of those 64 dependent dwordx4 loads is the only term big enough
// to explain the invariant 10.2 us/step).
//  - All 4 waves use the SAME A-fragments (lane-dependent, wave-independent)
//    -> stage the 32x1024 bf16 tile (64 KB) into LDS once, read per-step via
//    ds_read_b128 (~120cy, lgkmcnt-pipelined, off the MALL/sync path).
//  - Row stride padded to 1032 bf16 (2064 B = 129*16) -> fragment reads sit
//    at the conflict-free b128 baseline (4 lanes/16B-slot, the b128 minimum).
//  - Everything else identical to round 7 (packed flags, gx double-buffer,
//    publish-first store order, 32 up-front h loads, 4 MFMA chains).

#define B_  64
#define T_  256
#define ID_ 512
#define HD_ 1024
#define NG_ 4096
#define M1_ (B_ * T_)
#define NBLK 128
#define UPB  8

typedef __bf16 bf16x8 __attribute__((ext_vector_type(8)));
typedef float  f32x4  __attribute__((ext_vector_type(4)));
typedef int    i32x4  __attribute__((ext_vector_type(4)));
typedef int    i32x2  __attribute__((ext_vector_type(2)));
typedef short  s16x4  __attribute__((ext_vector_type(4)));

using bf16 = __hip_bfloat16;

__device__ __forceinline__ float sigmoid_fast(float x) {
    return 1.0f / (1.0f + __expf(-x));
}
__device__ __forceinline__ float tanh_fast(float x) {
    return 1.0f - 2.0f / (__expf(2.0f * x) + 1.0f);
}
__device__ __forceinline__ unsigned short bf16_bits(float x) {
    union { bf16 h; unsigned short u; } cv;
    cv.h = __float2bfloat16(x);
    return cv.u;
}
__device__ __forceinline__ bf16x8 vload8(const bf16* p) {
    union { i32x4 i; bf16x8 h; } cv;
    cv.i = *reinterpret_cast<const volatile i32x4*>(p);
    return cv.h;
}

// ---------------------------------------------------------------- prep ----
__global__ __launch_bounds__(256) void prep_kernel(
    const float* __restrict__ x, const float* __restrict__ Wi,
    const float* __restrict__ Wh, bf16* __restrict__ xb,
    bf16* __restrict__ wiT, bf16* __restrict__ whT,
    bf16* __restrict__ hbuf, int* __restrict__ flags) {
    const int tid = blockIdx.x * 256 + threadIdx.x;  // [0, 2097152)

    if (tid < NBLK * 4 * 16) flags[tid] = 0;          // covers packed flags
    if (tid < (B_ * HD_) / 4)                         // h[-1] = 0 (buf0)
        *reinterpret_cast<s16x4*>(hbuf + (size_t)tid * 4) = s16x4{0, 0, 0, 0};

    const float4 v = reinterpret_cast<const float4*>(x)[tid];
    bf16 tmp[4] = { __float2bfloat16(v.x), __float2bfloat16(v.y),
                    __float2bfloat16(v.z), __float2bfloat16(v.w) };
    *reinterpret_cast<s16x4*>(xb + 4 * (size_t)tid) =
        *reinterpret_cast<s16x4*>(tmp);

    {   // WiT[n][k] = Wi[k][n]
        const int n = tid >> 9, k = tid & 511;
        wiT[tid] = __float2bfloat16(Wi[(size_t)k * NG_ + n]);
    }
    for (int e = 0; e < 2; ++e) {  // WhT[n][k] = Wh[k][n]
        const int idx = 2 * tid + e;
        const int n = idx >> 10, k = idx & 1023;
        whT[idx] = __float2bfloat16(Wh[(size_t)k * NG_ + n]);
    }
}

// ---------------------------------------------------- phase-1 gates GEMM ----
// gates3 layout: [t][blk][tid(256)][8] bf16, e = nt*4+r in step-MFMA acc order.
__global__ __launch_bounds__(256) void gates_gemm_kernel(
    const bf16* __restrict__ xb, const bf16* __restrict__ wiT,
    const float* __restrict__ bi, const float* __restrict__ bh,
    bf16* __restrict__ gates3) {
    __shared__ __align__(16) bf16 As[128 * 40];
    __shared__ __align__(16) bf16 Bs[128 * 40];
    const int tid  = threadIdx.x;
    const int lane = tid & 63, wave = tid >> 6;
    const int wm = wave >> 1, wn = wave & 1;
    const int l15 = lane & 15, quad = lane >> 4;
    const int row0 = blockIdx.x * 128, col0 = blockIdx.y * 128;

    f32x4 acc[4][4];
    for (int i = 0; i < 4; ++i)
        for (int j = 0; j < 4; ++j) acc[i][j] = f32x4{0.f, 0.f, 0.f, 0.f};

    for (int kt = 0; kt < ID_ / 32; ++kt) {
        const int k0 = kt * 32;
        for (int L = tid; L < 512; L += 256) {
            const int r = L >> 2, s = L & 3;
            *reinterpret_cast<i32x4*>(&As[r * 40 + s * 8]) =
                *reinterpret_cast<const i32x4*>(xb + (size_t)(row0 + r) * ID_ + k0 + s * 8);
            *reinterpret_cast<i32x4*>(&Bs[r * 40 + s * 8]) =
                *reinterpret_cast<const i32x4*>(wiT + (size_t)(col0 + r) * ID_ + k0 + s * 8);
        }
        __syncthreads();
        bf16x8 af[4], bfv[4];
        for (int mt = 0; mt < 4; ++mt)
            af[mt] = *reinterpret_cast<const bf16x8*>(
                &As[(wm * 64 + mt * 16 + l15) * 40 + quad * 8]);
        for (int nt = 0; nt < 4; ++nt)
            bfv[nt] = *reinterpret_cast<const bf16x8*>(
                &Bs[(wn * 64 + nt * 16 + l15) * 40 + quad * 8]);
        for (int mt = 0; mt < 4; ++mt)
            for (int nt = 0; nt < 4; ++nt)
                acc[mt][nt] = __builtin_amdgcn_mfma_f32_16x16x32_bf16(
                    af[mt], bfv[nt], acc[mt][nt], 0, 0, 0);
        __syncthreads();
    }
    // epilogue: +(bi+bh), store to gates3 in persistent-kernel acc order
    for (int mt = 0; mt < 4; ++mt) {
        for (int nt = 0; nt < 4; ++nt) {
            const int cg = col0 + wn * 64 + nt * 16 + l15;
            const int g = cg >> 10, u = cg & 1023;
            const int blk = u >> 3, jl = u & 7;
            const int lcol = g * 8 + jl;               // m-index in step MFMA
            const int nt2 = lcol >> 4, q2 = (lcol >> 2) & 3, r2 = lcol & 3;
            const int e = nt2 * 4 + r2;
            const float bias = bi[cg] + bh[cg];
            for (int r = 0; r < 4; ++r) {
                const int rg = row0 + wm * 64 + mt * 16 + quad * 4 + r;
                const int b = rg >> 8, t = rg & 255;   // row = b*T + t
                const int tid2 = (b >> 4) * 64 + q2 * 16 + (b & 15);
                gates3[(((size_t)t * NBLK + blk) * 256 + tid2) * 8 + e] =
                    __float2bfloat16(acc[mt][nt][r] + bias);
            }
        }
    }
}

// ------------------------------------------------- persistent LSTM steps ----
// LDS A-tile: 32 rows (m = lcol) x 1024 k, padded stride 1032 bf16 (2064 B).
#define WHS_STRIDE 1032

__global__ __launch_bounds__(256, 1) void lstm_persistent_kernel(
    const bf16* __restrict__ gates3, const bf16* __restrict__ whT,
    bf16* __restrict__ hbuf, float* __restrict__ out, int* __restrict__ flags) {
    __shared__ __align__(16) bf16 whs[32 * WHS_STRIDE];   // 66048 B
    const int tid  = threadIdx.x;
    const int lane = tid & 63, w = tid >> 6;
    const int l15 = lane & 15, quad = lane >> 4;
    const int blk = blockIdx.x;                 // hidden units [blk*8, blk*8+8)

    // ---- stage Wh A-tile into LDS (once) ----
    // LDS row m (=lcol) <- whT row (m>>3)*HD + blk*8 + (m&7), 1024 bf16.
    for (int c = tid; c < 32 * 128; c += 256) {   // 16-B chunks
        const int m = c >> 7, col16 = c & 127;
        const size_t wrow = (size_t)((m >> 3) * HD_ + blk * UPB + (m & 7));
        *reinterpret_cast<i32x4*>(&whs[m * WHS_STRIDE + col16 * 8]) =
            *reinterpret_cast<const i32x4*>(whT + wrow * HD_ + col16 * 8);
    }
    __syncthreads();

    // per-lane fragment base pointers: row lcol = nt*16+l15, col quad*8 (+kk*32)
    const bf16* wa0 = &whs[(size_t)l15 * WHS_STRIDE + quad * 8];
    const bf16* wa1 = wa0 + 16 * WHS_STRIDE;

    // cell-update map (after shfl_xor(32) pairing quad<->quad^2):
    // thread covers (b = w*16+l15, units jl0, jl0+1)
    const int jl0 = 4 * (quad & 1) + 2 * (quad >> 1);
    const int b = w * 16 + l15;
    float c0 = 0.f, c1 = 0.f;

    // packed flags: flags[w*128 + blk]. Consumer lane polls blocks
    // 2*lane, 2*lane+1 of its own wave with a single dwordx2 load.
    const int* pollp = flags + (w << 7) + (lane << 1);

    // gx double-buffer: prefetch step 0 now; inside the loop step t+1 is
    // issued AFTER the flag publish so the pre-flag vmcnt(0) never waits
    // on an HBM load.
    bf16x8 gx_next = *reinterpret_cast<const bf16x8*>(
        gates3 + ((size_t)blk * 256 + tid) * 8);

    for (int t = 0; t < T_; ++t) {
        const bf16* hin  = hbuf + (size_t)(t & 1) * (B_ * HD_);
        bf16*       hout = hbuf + (size_t)((t + 1) & 1) * (B_ * HD_);
        const bf16x8 gx = gx_next;

        // wait until all blocks' wave w published h[t-1]
        if (t > 0) {
            for (;;) {
                i32x2 f = *reinterpret_cast<const volatile i32x2*>(pollp);
                if (f.x >= t && f.y >= t) break;
                __builtin_amdgcn_s_sleep(1);
            }
        }
        __asm__ __volatile__("" ::: "memory");   // no load hoisting above poll

        // ---- B-frags straight from global (volatile -> MALL), all 32 up
        //      front: pay MALL latency once, MFMAs pipeline on the returns.
        const bf16* hb_base = hin + (size_t)b * HD_ + quad * 8;
        bf16x8 hb[32];
#pragma unroll
        for (int kk = 0; kk < 32; ++kk)
            hb[kk] = vload8(hb_base + kk * 32);

        f32x4 a0e = f32x4{0.f, 0.f, 0.f, 0.f};
        f32x4 a0o = f32x4{0.f, 0.f, 0.f, 0.f};
        f32x4 a1e = f32x4{0.f, 0.f, 0.f, 0.f};
        f32x4 a1o = f32x4{0.f, 0.f, 0.f, 0.f};
#pragma unroll
        for (int kk = 0; kk < 32; kk += 2) {
            const bf16x8 w0e = *reinterpret_cast<const bf16x8*>(wa0 + kk * 32);
            const bf16x8 w1e = *reinterpret_cast<const bf16x8*>(wa1 + kk * 32);
            const bf16x8 w0o = *reinterpret_cast<const bf16x8*>(wa0 + (kk + 1) * 32);
            const bf16x8 w1o = *reinterpret_cast<const bf16x8*>(wa1 + (kk + 1) * 32);
            a0e = __builtin_amdgcn_mfma_f32_16x16x32_bf16(w0e, hb[kk], a0e, 0, 0, 0);
            a1e = __builtin_amdgcn_mfma_f32_16x16x32_bf16(w1e, hb[kk], a1e, 0, 0, 0);
            a0o = __builtin_amdgcn_mfma_f32_16x16x32_bf16(w0o, hb[kk + 1], a0o, 0, 0, 0);
            a1o = __builtin_amdgcn_mfma_f32_16x16x32_bf16(w1o, hb[kk + 1], a1o, 0, 0, 0);
        }
        const f32x4 acc0 = a0e + a0o;
        const f32x4 acc1 = a1e + a1o;

        // ---- activations (own 8 lcols: acc0 -> lcol=quad*4+r, acc1 -> +16) ----
        float v0[4], v1[4];
#pragma unroll
        for (int r = 0; r < 4; ++r) {
            const float p0 = acc0[r] + (float)gx[r];
            const float p1 = acc1[r] + (float)gx[4 + r];
            v0[r] = sigmoid_fast(p0);                              // F or I
            v1[r] = (quad < 2) ? tanh_fast(p1) : sigmoid_fast(p1); // A or O
        }
        // ---- exchange with quad^2 partner (lane ^ 32) ----
        float u0[4], u1[4];
#pragma unroll
        for (int r = 0; r < 4; ++r) {
            u0[r] = __shfl_xor(v0[r], 32, 64);
            u1[r] = __shfl_xor(v1[r], 32, 64);
        }
        const int rsel = 2 * (quad >> 1);
        const float f0 = (quad < 2) ? v0[rsel]     : u0[rsel];
        const float i0 = (quad < 2) ? u0[rsel]     : v0[rsel];
        const float a0 = (quad < 2) ? v1[rsel]     : u1[rsel];
        const float o0 = (quad < 2) ? u1[rsel]     : v1[rsel];
        const float f1 = (quad < 2) ? v0[rsel + 1] : u0[rsel + 1];
        const float i1 = (quad < 2) ? u0[rsel + 1] : v0[rsel + 1];
        const float a1 = (quad < 2) ? v1[rsel + 1] : u1[rsel + 1];
        const float o1 = (quad < 2) ? u1[rsel + 1] : v1[rsel + 1];

        const float cn0 = f0 * c0 + i0 * a0;  c0 = cn0;
        const float cn1 = f1 * c1 + i1 * a1;  c1 = cn1;
        const float h0 = o0 * tanh_fast(cn0);
        const float h1 = o1 * tanh_fast(cn1);

        const int hidx = b * HD_ + blk * UPB + jl0;
        if (t < T_ - 1) {
            // publish h first: drain covers ONLY this one MALL store ack.
            const unsigned int packed =
                (unsigned int)bf16_bits(h0) | ((unsigned int)bf16_bits(h1) << 16);
            *reinterpret_cast<volatile unsigned int*>(hout + hidx) = packed;
            __asm__ __volatile__("s_waitcnt vmcnt(0)" ::: "memory");
            if (lane == 0)
                *reinterpret_cast<volatile int*>(flags + (w << 7) + blk) = t + 1;
            __asm__ __volatile__("" ::: "memory");
            // prefetch next step's gx now: a full step of latency to hide,
            // and it is never caught by a pre-flag drain.
            gx_next = *reinterpret_cast<const bf16x8*>(
                gates3 + (((size_t)(t + 1) * NBLK + blk) * 256 + tid) * 8);
        }
        // out stores off the inter-block critical path (after flag publish)
        *reinterpret_cast<float2*>(
            out + ((size_t)b * T_ + t) * HD_ + blk * UPB + jl0) =
            make_float2(h0, h1);
        if (t == T_ - 1) {
            *reinterpret_cast<float2*>(out + (size_t)M1_ * HD_ + hidx) =
                make_float2(h0, h1);
            *reinterpret_cast<float2*>(
                out + (size_t)M1_ * HD_ + B_ * HD_ + hidx) =
                make_float2(cn0, cn1);
        }
    }
}

// -------------------------------------------------------------- launcher ----
extern "C" void kernel_launch(void* const* d_in, const int* in_sizes, int n_in,
                              void* d_out, int out_size, void* d_ws, size_t ws_size,
                              hipStream_t stream) {
    const float* x  = (const float*)d_in[0];
    const float* Wi = (const float*)d_in[1];
    const float* bi = (const float*)d_in[2];
    const float* Wh = (const float*)d_in[3];
    const float* bh = (const float*)d_in[4];
    float* out = (float*)d_out;

    char* ws = (char*)d_ws;
    size_t off = 0;
    bf16* xb     = (bf16*)(ws + off); off += (size_t)M1_ * ID_ * 2;       // 16 MB
    bf16* wiT    = (bf16*)(ws + off); off += (size_t)NG_ * ID_ * 2;       // 4 MB
    bf16* whT    = (bf16*)(ws + off); off += (size_t)NG_ * HD_ * 2;       // 8 MB
    bf16* gates3 = (bf16*)(ws + off); off += (size_t)T_ * B_ * NG_ * 2;   // 128 MB
    bf16* hbuf   = (bf16*)(ws + off); off += (size_t)2 * B_ * HD_ * 2;    // 256 KB
    int* flags   = (int*)(ws + off);  off += (size_t)NBLK * 4 * 16 * 4;   // 32 KB

    prep_kernel<<<8192, 256, 0, stream>>>(x, Wi, Wh, xb, wiT, whT, hbuf, flags);
    gates_gemm_kernel<<<dim3(128, 32), 256, 0, stream>>>(xb, wiT, bi, bh, gates3);

    lstm_persistent_kernel<<<dim3(NBLK), dim3(256), 0, stream>>>(
        gates3, whT, hbuf, out, flags);
}

// Round 5
// 2651.328 us; speedup vs baseline: 1.2321x; 1.2321x over previous
//
#include <hip/hip_runtime.h>
#include <hip/hip_bf16.h>

// LSTM B=64, T=256, ID=512, HD=1024. Gates F,I,A,O.
// Round 9: the 10.2us/step invariant across r5-r8 is the VOLATILE h-loads.
// LLVM AMDGPU emits each volatile global_load with its own s_waitcnt vmcnt(0)
// (strong ordering), serializing 32 MALL round-trips per step:
// 32 x ~800cy = ~25.6k cy = ~10.7us -- exactly the observed step time, and
// why no Wh-path change (regs r5-r7, LDS r8) ever moved the needle.
//  (1) h loads -> inline-asm global_load_dwordx4 sc0 sc1 (same coherence
//      bits volatile used, so cross-XCD visibility is preserved), 32 issued
//      back-to-back, ONE s_waitcnt vmcnt(0) + sched_barrier(0) before MFMAs.
//  (2) LDS Wh tile re-laid-out: lane's fragment at byte kk*2048+sel*1024+
//      lane*16 -> lane i reads byte 16*i (contiguous, conflict-free b128
//      baseline). r8's 2064-B row stride caused 3.36e7 bank conflicts.
//  (3) Everything else as r7/r8: packed flags, gx double-buffer, publish-
//      first store order, 4 independent MFMA chains.

#define B_  64
#define T_  256
#define ID_ 512
#define HD_ 1024
#define NG_ 4096
#define M1_ (B_ * T_)
#define NBLK 128
#define UPB  8

typedef __bf16 bf16x8 __attribute__((ext_vector_type(8)));
typedef float  f32x4  __attribute__((ext_vector_type(4)));
typedef int    i32x4  __attribute__((ext_vector_type(4)));
typedef int    i32x2  __attribute__((ext_vector_type(2)));
typedef short  s16x4  __attribute__((ext_vector_type(4)));

using bf16 = __hip_bfloat16;

__device__ __forceinline__ float sigmoid_fast(float x) {
    return 1.0f / (1.0f + __expf(-x));
}
__device__ __forceinline__ float tanh_fast(float x) {
    return 1.0f - 2.0f / (__expf(2.0f * x) + 1.0f);
}
__device__ __forceinline__ unsigned short bf16_bits(float x) {
    union { bf16 h; unsigned short u; } cv;
    cv.h = __float2bfloat16(x);
    return cv.u;
}
__device__ __forceinline__ bf16x8 as_bf16x8(i32x4 v) {
    union { i32x4 i; bf16x8 h; } cv;
    cv.i = v;
    return cv.h;
}

// ---------------------------------------------------------------- prep ----
__global__ __launch_bounds__(256) void prep_kernel(
    const float* __restrict__ x, const float* __restrict__ Wi,
    const float* __restrict__ Wh, bf16* __restrict__ xb,
    bf16* __restrict__ wiT, bf16* __restrict__ whT,
    bf16* __restrict__ hbuf, int* __restrict__ flags) {
    const int tid = blockIdx.x * 256 + threadIdx.x;  // [0, 2097152)

    if (tid < NBLK * 4 * 16) flags[tid] = 0;          // covers packed flags
    if (tid < (B_ * HD_) / 4)                         // h[-1] = 0 (buf0)
        *reinterpret_cast<s16x4*>(hbuf + (size_t)tid * 4) = s16x4{0, 0, 0, 0};

    const float4 v = reinterpret_cast<const float4*>(x)[tid];
    bf16 tmp[4] = { __float2bfloat16(v.x), __float2bfloat16(v.y),
                    __float2bfloat16(v.z), __float2bfloat16(v.w) };
    *reinterpret_cast<s16x4*>(xb + 4 * (size_t)tid) =
        *reinterpret_cast<s16x4*>(tmp);

    {   // WiT[n][k] = Wi[k][n]
        const int n = tid >> 9, k = tid & 511;
        wiT[tid] = __float2bfloat16(Wi[(size_t)k * NG_ + n]);
    }
    for (int e = 0; e < 2; ++e) {  // WhT[n][k] = Wh[k][n]
        const int idx = 2 * tid + e;
        const int n = idx >> 10, k = idx & 1023;
        whT[idx] = __float2bfloat16(Wh[(size_t)k * NG_ + n]);
    }
}

// ---------------------------------------------------- phase-1 gates GEMM ----
// gates3 layout: [t][blk][tid(256)][8] bf16, e = nt*4+r in step-MFMA acc order.
__global__ __launch_bounds__(256) void gates_gemm_kernel(
    const bf16* __restrict__ xb, const bf16* __restrict__ wiT,
    const float* __restrict__ bi, const float* __restrict__ bh,
    bf16* __restrict__ gates3) {
    __shared__ __align__(16) bf16 As[128 * 40];
    __shared__ __align__(16) bf16 Bs[128 * 40];
    const int tid  = threadIdx.x;
    const int lane = tid & 63, wave = tid >> 6;
    const int wm = wave >> 1, wn = wave & 1;
    const int l15 = lane & 15, quad = lane >> 4;
    const int row0 = blockIdx.x * 128, col0 = blockIdx.y * 128;

    f32x4 acc[4][4];
    for (int i = 0; i < 4; ++i)
        for (int j = 0; j < 4; ++j) acc[i][j] = f32x4{0.f, 0.f, 0.f, 0.f};

    for (int kt = 0; kt < ID_ / 32; ++kt) {
        const int k0 = kt * 32;
        for (int L = tid; L < 512; L += 256) {
            const int r = L >> 2, s = L & 3;
            *reinterpret_cast<i32x4*>(&As[r * 40 + s * 8]) =
                *reinterpret_cast<const i32x4*>(xb + (size_t)(row0 + r) * ID_ + k0 + s * 8);
            *reinterpret_cast<i32x4*>(&Bs[r * 40 + s * 8]) =
                *reinterpret_cast<const i32x4*>(wiT + (size_t)(col0 + r) * ID_ + k0 + s * 8);
        }
        __syncthreads();
        bf16x8 af[4], bfv[4];
        for (int mt = 0; mt < 4; ++mt)
            af[mt] = *reinterpret_cast<const bf16x8*>(
                &As[(wm * 64 + mt * 16 + l15) * 40 + quad * 8]);
        for (int nt = 0; nt < 4; ++nt)
            bfv[nt] = *reinterpret_cast<const bf16x8*>(
                &Bs[(wn * 64 + nt * 16 + l15) * 40 + quad * 8]);
        for (int mt = 0; mt < 4; ++mt)
            for (int nt = 0; nt < 4; ++nt)
                acc[mt][nt] = __builtin_amdgcn_mfma_f32_16x16x32_bf16(
                    af[mt], bfv[nt], acc[mt][nt], 0, 0, 0);
        __syncthreads();
    }
    // epilogue: +(bi+bh), store to gates3 in persistent-kernel acc order
    for (int mt = 0; mt < 4; ++mt) {
        for (int nt = 0; nt < 4; ++nt) {
            const int cg = col0 + wn * 64 + nt * 16 + l15;
            const int g = cg >> 10, u = cg & 1023;
            const int blk = u >> 3, jl = u & 7;
            const int lcol = g * 8 + jl;               // m-index in step MFMA
            const int nt2 = lcol >> 4, q2 = (lcol >> 2) & 3, r2 = lcol & 3;
            const int e = nt2 * 4 + r2;
            const float bias = bi[cg] + bh[cg];
            for (int r = 0; r < 4; ++r) {
                const int rg = row0 + wm * 64 + mt * 16 + quad * 4 + r;
                const int b = rg >> 8, t = rg & 255;   // row = b*T + t
                const int tid2 = (b >> 4) * 64 + q2 * 16 + (b & 15);
                gates3[(((size_t)t * NBLK + blk) * 256 + tid2) * 8 + e] =
                    __float2bfloat16(acc[mt][nt][r] + bias);
            }
        }
    }
}

// ------------------------------------------------- persistent LSTM steps ----
// LDS Wh tile layout: byte = kk*2048 + sel*1024 + lane*16  (kk=0..31, sel=0/1
// for the two m-halves, lane=0..63). Lane i always reads byte 16*i within a
// 1024-B slab -> contiguous conflict-free b128 pattern by construction.
__global__ __launch_bounds__(256, 1) void lstm_persistent_kernel(
    const bf16* __restrict__ gates3, const bf16* __restrict__ whT,
    bf16* __restrict__ hbuf, float* __restrict__ out, int* __restrict__ flags) {
    __shared__ __align__(16) bf16 whs[32 * 2 * 64 * 8];   // 64 KB
    const int tid  = threadIdx.x;
    const int lane = tid & 63, w = tid >> 6;
    const int l15 = lane & 15, quad = lane >> 4;
    const int blk = blockIdx.x;                 // hidden units [blk*8, blk*8+8)

    // ---- stage Wh A-tile into LDS (once), linear-in-tid writes ----
    // chunk c (16 B): kk = c>>7, sel = (c>>6)&1, ln = c&63.
    // holds whT row (sel*16 + (ln&15)) mapped row, col (ln>>4)*8 + kk*32.
    for (int c = tid; c < 4096; c += 256) {
        const int kk = c >> 7, sel = (c >> 6) & 1, ln = c & 63;
        const int m = sel * 16 + (ln & 15);
        const size_t wrow = (size_t)((m >> 3) * HD_ + blk * UPB + (m & 7));
        const int col = (ln >> 4) * 8 + kk * 32;
        *reinterpret_cast<i32x4*>(whs + (size_t)c * 8) =
            *reinterpret_cast<const i32x4*>(whT + wrow * HD_ + col);
    }
    __syncthreads();

    const bf16* wb = whs + (size_t)lane * 8;   // + kk*1024 (+512 for sel=1)

    // cell-update map (after shfl_xor(32) pairing quad<->quad^2):
    // thread covers (b = w*16+l15, units jl0, jl0+1)
    const int jl0 = 4 * (quad & 1) + 2 * (quad >> 1);
    const int b = w * 16 + l15;
    float c0 = 0.f, c1 = 0.f;

    // packed flags: flags[w*128 + blk]. Consumer lane polls blocks
    // 2*lane, 2*lane+1 of its own wave with a single dwordx2 load.
    const int* pollp = flags + (w << 7) + (lane << 1);

    // gx double-buffer: prefetch step 0 now; inside the loop step t+1 is
    // issued AFTER the flag publish so the pre-flag vmcnt(0) never waits
    // on an HBM load.
    bf16x8 gx_next = *reinterpret_cast<const bf16x8*>(
        gates3 + ((size_t)blk * 256 + tid) * 8);

    for (int t = 0; t < T_; ++t) {
        const bf16* hin  = hbuf + (size_t)(t & 1) * (B_ * HD_);
        bf16*       hout = hbuf + (size_t)((t + 1) & 1) * (B_ * HD_);
        const bf16x8 gx = gx_next;

        // wait until all blocks' wave w published h[t-1]
        if (t > 0) {
            for (;;) {
                i32x2 f = *reinterpret_cast<const volatile i32x2*>(pollp);
                if (f.x >= t && f.y >= t) break;
                __builtin_amdgcn_s_sleep(1);
            }
        }
        __asm__ __volatile__("" ::: "memory");   // no load hoisting above poll

        // ---- h B-frags: 32 coherent loads (sc0 sc1 = bypass L1/L2, read
        //      MALL like volatile did) issued back-to-back, ONE vmcnt(0).
        //      This was the 10us/step bug: volatile = 32 SERIAL round-trips.
        const bf16* hb_base = hin + (size_t)b * HD_ + quad * 8;
        i32x4 hb[32];
#pragma unroll
        for (int kk = 0; kk < 32; ++kk) {
            asm volatile("global_load_dwordx4 %0, %1, off sc0 sc1"
                         : "=v"(hb[kk])
                         : "v"(hb_base + kk * 32));
        }
        asm volatile("s_waitcnt vmcnt(0)" ::: "memory");
        __builtin_amdgcn_sched_barrier(0);   // rule #18: pin MFMAs below wait

        f32x4 a0e = f32x4{0.f, 0.f, 0.f, 0.f};
        f32x4 a0o = f32x4{0.f, 0.f, 0.f, 0.f};
        f32x4 a1e = f32x4{0.f, 0.f, 0.f, 0.f};
        f32x4 a1o = f32x4{0.f, 0.f, 0.f, 0.f};
#pragma unroll
        for (int kk = 0; kk < 32; kk += 2) {
            const bf16x8 w0e = *reinterpret_cast<const bf16x8*>(wb + kk * 1024);
            const bf16x8 w1e = *reinterpret_cast<const bf16x8*>(wb + kk * 1024 + 512);
            const bf16x8 w0o = *reinterpret_cast<const bf16x8*>(wb + (kk + 1) * 1024);
            const bf16x8 w1o = *reinterpret_cast<const bf16x8*>(wb + (kk + 1) * 1024 + 512);
            a0e = __builtin_amdgcn_mfma_f32_16x16x32_bf16(w0e, as_bf16x8(hb[kk]), a0e, 0, 0, 0);
            a1e = __builtin_amdgcn_mfma_f32_16x16x32_bf16(w1e, as_bf16x8(hb[kk]), a1e, 0, 0, 0);
            a0o = __builtin_amdgcn_mfma_f32_16x16x32_bf16(w0o, as_bf16x8(hb[kk + 1]), a0o, 0, 0, 0);
            a1o = __builtin_amdgcn_mfma_f32_16x16x32_bf16(w1o, as_bf16x8(hb[kk + 1]), a1o, 0, 0, 0);
        }
        const f32x4 acc0 = a0e + a0o;
        const f32x4 acc1 = a1e + a1o;

        // ---- activations (own 8 lcols: acc0 -> lcol=quad*4+r, acc1 -> +16) ----
        float v0[4], v1[4];
#pragma unroll
        for (int r = 0; r < 4; ++r) {
            const float p0 = acc0[r] + (float)gx[r];
            const float p1 = acc1[r] + (float)gx[4 + r];
            v0[r] = sigmoid_fast(p0);                              // F or I
            v1[r] = (quad < 2) ? tanh_fast(p1) : sigmoid_fast(p1); // A or O
        }
        // ---- exchange with quad^2 partner (lane ^ 32) ----
        float u0[4], u1[4];
#pragma unroll
        for (int r = 0; r < 4; ++r) {
            u0[r] = __shfl_xor(v0[r], 32, 64);
            u1[r] = __shfl_xor(v1[r], 32, 64);
        }
        const int rsel = 2 * (quad >> 1);
        const float f0 = (quad < 2) ? v0[rsel]     : u0[rsel];
        const float i0 = (quad < 2) ? u0[rsel]     : v0[rsel];
        const float a0 = (quad < 2) ? v1[rsel]     : u1[rsel];
        const float o0 = (quad < 2) ? u1[rsel]     : v1[rsel];
        const float f1 = (quad < 2) ? v0[rsel + 1] : u0[rsel + 1];
        const float i1 = (quad < 2) ? u0[rsel + 1] : v0[rsel + 1];
        const float a1 = (quad < 2) ? v1[rsel + 1] : u1[rsel + 1];
        const float o1 = (quad < 2) ? u1[rsel + 1] : v1[rsel + 1];

        const float cn0 = f0 * c0 + i0 * a0;  c0 = cn0;
        const float cn1 = f1 * c1 + i1 * a1;  c1 = cn1;
        const float h0 = o0 * tanh_fast(cn0);
        const float h1 = o1 * tanh_fast(cn1);

        const int hidx = b * HD_ + blk * UPB + jl0;
        if (t < T_ - 1) {
            // publish h first: drain covers ONLY this one MALL store ack.
            const unsigned int packed =
                (unsigned int)bf16_bits(h0) | ((unsigned int)bf16_bits(h1) << 16);
            *reinterpret_cast<volatile unsigned int*>(hout + hidx) = packed;
            __asm__ __volatile__("s_waitcnt vmcnt(0)" ::: "memory");
            if (lane == 0)
                *reinterpret_cast<volatile int*>(flags + (w << 7) + blk) = t + 1;
            __asm__ __volatile__("" ::: "memory");
            // prefetch next step's gx now: a full step of latency to hide,
            // and it is never caught by a pre-flag drain.
            gx_next = *reinterpret_cast<const bf16x8*>(
                gates3 + (((size_t)(t + 1) * NBLK + blk) * 256 + tid) * 8);
        }
        // out stores off the inter-block critical path (after flag publish)
        *reinterpret_cast<float2*>(
            out + ((size_t)b * T_ + t) * HD_ + blk * UPB + jl0) =
            make_float2(h0, h1);
        if (t == T_ - 1) {
            *reinterpret_cast<float2*>(out + (size_t)M1_ * HD_ + hidx) =
                make_float2(h0, h1);
            *reinterpret_cast<float2*>(
                out + (size_t)M1_ * HD_ + B_ * HD_ + hidx) =
                make_float2(cn0, cn1);
        }
    }
}

// -------------------------------------------------------------- launcher ----
extern "C" void kernel_launch(void* const* d_in, const int* in_sizes, int n_in,
                              void* d_out, int out_size, void* d_ws, size_t ws_size,
                              hipStream_t stream) {
    const float* x  = (const float*)d_in[0];
    const float* Wi = (const float*)d_in[1];
    const float* bi = (const float*)d_in[2];
    const float* Wh = (const float*)d_in[3];
    const float* bh = (const float*)d_in[4];
    float* out = (float*)d_out;

    char* ws = (char*)d_ws;
    size_t off = 0;
    bf16* xb     = (bf16*)(ws + off); off += (size_t)M1_ * ID_ * 2;       // 16 MB
    bf16* wiT    = (bf16*)(ws + off); off += (size_t)NG_ * ID_ * 2;       // 4 MB
    bf16* whT    = (bf16*)(ws + off); off += (size_t)NG_ * HD_ * 2;       // 8 MB
    bf16* gates3 = (bf16*)(ws + off); off += (size_t)T_ * B_ * NG_ * 2;   // 128 MB
    bf16* hbuf   = (bf16*)(ws + off); off += (size_t)2 * B_ * HD_ * 2;    // 256 KB
    int* flags   = (int*)(ws + off);  off += (size_t)NBLK * 4 * 16 * 4;   // 32 KB

    prep_kernel<<<8192, 256, 0, stream>>>(x, Wi, Wh, xb, wiT, whT, hbuf, flags);
    gates_gemm_kernel<<<dim3(128, 32), 256, 0, stream>>>(xb, wiT, bi, bh, gates3);

    lstm_persistent_kernel<<<dim3(NBLK), dim3(256), 0, stream>>>(
        gates3, whT, hbuf, out, flags);
}

// Round 7
// 2561.496 us; speedup vs baseline: 1.2753x; 1.0351x over previous
//
#include <hip/hip_runtime.h>
#include <hip/hip_bf16.h>

// LSTM B=64, T=256, ID=512, HD=1024. Gates F,I,A,O.
// Round 11: r10 + the missing EARLY-CLOBBER on issue8 outputs.
// r10 crashed (GPU memory fault -> pytest abort): with plain "=v" outputs,
// LLVM may alias an output tuple with the %8 address pair (legal under the
// "inputs read before outputs written" assumption, which multi-instruction
// load blocks violate: load #1's return clobbers the address for loads
// #2-8 -> wild addresses). r9's single-load asm was safe; r10's 8-load
// block was not. "=&v" forces disjoint allocation.
// Structure (unchanged from r10):
//  (1) h loads: two ping-pong groups of 8 (hbA/hbB, 64 VGPRs total), each
//      issued as one asm block (one base + offset: immediates), counted
//      s_waitcnt vmcnt(8) between groups (T4), vmcnt(0) only for the last.
//      sched_barrier(0) after each wait (rule #18).
//  (2) Wh in conflict-free LDS layout (r9: 0 bank conflicts).
//  (3) Packed flags, gx double-buffer, publish-first store order, 4
//      independent MFMA chains.

#define B_  64
#define T_  256
#define ID_ 512
#define HD_ 1024
#define NG_ 4096
#define M1_ (B_ * T_)
#define NBLK 128
#define UPB  8

typedef __bf16 bf16x8 __attribute__((ext_vector_type(8)));
typedef float  f32x4  __attribute__((ext_vector_type(4)));
typedef int    i32x4  __attribute__((ext_vector_type(4)));
typedef int    i32x2  __attribute__((ext_vector_type(2)));
typedef short  s16x4  __attribute__((ext_vector_type(4)));

using bf16 = __hip_bfloat16;

__device__ __forceinline__ float sigmoid_fast(float x) {
    return 1.0f / (1.0f + __expf(-x));
}
__device__ __forceinline__ float tanh_fast(float x) {
    return 1.0f - 2.0f / (__expf(2.0f * x) + 1.0f);
}
__device__ __forceinline__ unsigned short bf16_bits(float x) {
    union { bf16 h; unsigned short u; } cv;
    cv.h = __float2bfloat16(x);
    return cv.u;
}
__device__ __forceinline__ bf16x8 as_bf16x8(i32x4 v) {
    union { i32x4 i; bf16x8 h; } cv;
    cv.i = v;
    return cv.h;
}

// 8 coherent 16-B loads from one base (offsets 0..448 B), one asm block.
// "=&v" EARLY-CLOBBER is load-bearing: outputs must not alias the address
// pair (loads 2-8 read %8 after load 1's data can return).
__device__ __forceinline__ void issue8(i32x4* dst, const bf16* gbase) {
    asm volatile(
        "global_load_dwordx4 %0, %8, off sc0 sc1\n\t"
        "global_load_dwordx4 %1, %8, off offset:64 sc0 sc1\n\t"
        "global_load_dwordx4 %2, %8, off offset:128 sc0 sc1\n\t"
        "global_load_dwordx4 %3, %8, off offset:192 sc0 sc1\n\t"
        "global_load_dwordx4 %4, %8, off offset:256 sc0 sc1\n\t"
        "global_load_dwordx4 %5, %8, off offset:320 sc0 sc1\n\t"
        "global_load_dwordx4 %6, %8, off offset:384 sc0 sc1\n\t"
        "global_load_dwordx4 %7, %8, off offset:448 sc0 sc1"
        : "=&v"(dst[0]), "=&v"(dst[1]), "=&v"(dst[2]), "=&v"(dst[3]),
          "=&v"(dst[4]), "=&v"(dst[5]), "=&v"(dst[6]), "=&v"(dst[7])
        : "v"(gbase));
}

// ---------------------------------------------------------------- prep ----
__global__ __launch_bounds__(256) void prep_kernel(
    const float* __restrict__ x, const float* __restrict__ Wi,
    const float* __restrict__ Wh, bf16* __restrict__ xb,
    bf16* __restrict__ wiT, bf16* __restrict__ whT,
    bf16* __restrict__ hbuf, int* __restrict__ flags) {
    const int tid = blockIdx.x * 256 + threadIdx.x;  // [0, 2097152)

    if (tid < NBLK * 4 * 16) flags[tid] = 0;          // covers packed flags
    if (tid < (B_ * HD_) / 4)                         // h[-1] = 0 (buf0)
        *reinterpret_cast<s16x4*>(hbuf + (size_t)tid * 4) = s16x4{0, 0, 0, 0};

    const float4 v = reinterpret_cast<const float4*>(x)[tid];
    bf16 tmp[4] = { __float2bfloat16(v.x), __float2bfloat16(v.y),
                    __float2bfloat16(v.z), __float2bfloat16(v.w) };
    *reinterpret_cast<s16x4*>(xb + 4 * (size_t)tid) =
        *reinterpret_cast<s16x4*>(tmp);

    {   // WiT[n][k] = Wi[k][n]
        const int n = tid >> 9, k = tid & 511;
        wiT[tid] = __float2bfloat16(Wi[(size_t)k * NG_ + n]);
    }
    for (int e = 0; e < 2; ++e) {  // WhT[n][k] = Wh[k][n]
        const int idx = 2 * tid + e;
        const int n = idx >> 10, k = idx & 1023;
        whT[idx] = __float2bfloat16(Wh[(size_t)k * NG_ + n]);
    }
}

// ---------------------------------------------------- phase-1 gates GEMM ----
// gates3 layout: [t][blk][tid(256)][8] bf16, e = nt*4+r in step-MFMA acc order.
__global__ __launch_bounds__(256) void gates_gemm_kernel(
    const bf16* __restrict__ xb, const bf16* __restrict__ wiT,
    const float* __restrict__ bi, const float* __restrict__ bh,
    bf16* __restrict__ gates3) {
    __shared__ __align__(16) bf16 As[128 * 40];
    __shared__ __align__(16) bf16 Bs[128 * 40];
    const int tid  = threadIdx.x;
    const int lane = tid & 63, wave = tid >> 6;
    const int wm = wave >> 1, wn = wave & 1;
    const int l15 = lane & 15, quad = lane >> 4;
    const int row0 = blockIdx.x * 128, col0 = blockIdx.y * 128;

    f32x4 acc[4][4];
    for (int i = 0; i < 4; ++i)
        for (int j = 0; j < 4; ++j) acc[i][j] = f32x4{0.f, 0.f, 0.f, 0.f};

    for (int kt = 0; kt < ID_ / 32; ++kt) {
        const int k0 = kt * 32;
        for (int L = tid; L < 512; L += 256) {
            const int r = L >> 2, s = L & 3;
            *reinterpret_cast<i32x4*>(&As[r * 40 + s * 8]) =
                *reinterpret_cast<const i32x4*>(xb + (size_t)(row0 + r) * ID_ + k0 + s * 8);
            *reinterpret_cast<i32x4*>(&Bs[r * 40 + s * 8]) =
                *reinterpret_cast<const i32x4*>(wiT + (size_t)(col0 + r) * ID_ + k0 + s * 8);
        }
        __syncthreads();
        bf16x8 af[4], bfv[4];
        for (int mt = 0; mt < 4; ++mt)
            af[mt] = *reinterpret_cast<const bf16x8*>(
                &As[(wm * 64 + mt * 16 + l15) * 40 + quad * 8]);
        for (int nt = 0; nt < 4; ++nt)
            bfv[nt] = *reinterpret_cast<const bf16x8*>(
                &Bs[(wn * 64 + nt * 16 + l15) * 40 + quad * 8]);
        for (int mt = 0; mt < 4; ++mt)
            for (int nt = 0; nt < 4; ++nt)
                acc[mt][nt] = __builtin_amdgcn_mfma_f32_16x16x32_bf16(
                    af[mt], bfv[nt], acc[mt][nt], 0, 0, 0);
        __syncthreads();
    }
    // epilogue: +(bi+bh), store to gates3 in persistent-kernel acc order
    for (int mt = 0; mt < 4; ++mt) {
        for (int nt = 0; nt < 4; ++nt) {
            const int cg = col0 + wn * 64 + nt * 16 + l15;
            const int g = cg >> 10, u = cg & 1023;
            const int blk = u >> 3, jl = u & 7;
            const int lcol = g * 8 + jl;               // m-index in step MFMA
            const int nt2 = lcol >> 4, q2 = (lcol >> 2) & 3, r2 = lcol & 3;
            const int e = nt2 * 4 + r2;
            const float bias = bi[cg] + bh[cg];
            for (int r = 0; r < 4; ++r) {
                const int rg = row0 + wm * 64 + mt * 16 + quad * 4 + r;
                const int b = rg >> 8, t = rg & 255;   // row = b*T + t
                const int tid2 = (b >> 4) * 64 + q2 * 16 + (b & 15);
                gates3[(((size_t)t * NBLK + blk) * 256 + tid2) * 8 + e] =
                    __float2bfloat16(acc[mt][nt][r] + bias);
            }
        }
    }
}

// ------------------------------------------------- persistent LSTM steps ----
// LDS Wh tile layout: byte = kk*2048 + sel*1024 + lane*16  (kk=0..31, sel=0/1
// for the two m-halves, lane=0..63). Lane i always reads byte 16*i within a
// 1024-B slab -> contiguous conflict-free b128 pattern by construction.
__global__ __launch_bounds__(256, 1) void lstm_persistent_kernel(
    const bf16* __restrict__ gates3, const bf16* __restrict__ whT,
    bf16* __restrict__ hbuf, float* __restrict__ out, int* __restrict__ flags) {
    __shared__ __align__(16) bf16 whs[32 * 2 * 64 * 8];   // 64 KB
    const int tid  = threadIdx.x;
    const int lane = tid & 63, w = tid >> 6;
    const int l15 = lane & 15, quad = lane >> 4;
    const int blk = blockIdx.x;                 // hidden units [blk*8, blk*8+8)

    // ---- stage Wh A-tile into LDS (once), linear-in-tid writes ----
    for (int c = tid; c < 4096; c += 256) {
        const int kk = c >> 7, sel = (c >> 6) & 1, ln = c & 63;
        const int m = sel * 16 + (ln & 15);
        const size_t wrow = (size_t)((m >> 3) * HD_ + blk * UPB + (m & 7));
        const int col = (ln >> 4) * 8 + kk * 32;
        *reinterpret_cast<i32x4*>(whs + (size_t)c * 8) =
            *reinterpret_cast<const i32x4*>(whT + wrow * HD_ + col);
    }
    __syncthreads();

    const bf16* wb = whs + (size_t)lane * 8;   // + kk*1024 (+512 for sel=1)

    // cell-update map (after shfl_xor(32) pairing quad<->quad^2):
    // thread covers (b = w*16+l15, units jl0, jl0+1)
    const int jl0 = 4 * (quad & 1) + 2 * (quad >> 1);
    const int b = w * 16 + l15;
    float c0 = 0.f, c1 = 0.f;

    // packed flags: flags[w*128 + blk]. Consumer lane polls blocks
    // 2*lane, 2*lane+1 of its own wave with a single dwordx2 load.
    const int* pollp = flags + (w << 7) + (lane << 1);

    // gx double-buffer: prefetch step 0 now; inside the loop step t+1 is
    // issued AFTER the flag publish so the pre-flag vmcnt(0) never waits
    // on an HBM load.
    bf16x8 gx_next = *reinterpret_cast<const bf16x8*>(
        gates3 + ((size_t)blk * 256 + tid) * 8);

    for (int t = 0; t < T_; ++t) {
        const bf16* hin  = hbuf + (size_t)(t & 1) * (B_ * HD_);
        bf16*       hout = hbuf + (size_t)((t + 1) & 1) * (B_ * HD_);
        const bf16x8 gx = gx_next;

        // wait until all blocks' wave w published h[t-1]
        if (t > 0) {
            for (;;) {
                i32x2 f = *reinterpret_cast<const volatile i32x2*>(pollp);
                if (f.x >= t && f.y >= t) break;
                __builtin_amdgcn_s_sleep(1);
            }
        }
        __asm__ __volatile__("" ::: "memory");   // no load hoisting above poll

        f32x4 a0e = f32x4{0.f, 0.f, 0.f, 0.f};
        f32x4 a0o = f32x4{0.f, 0.f, 0.f, 0.f};
        f32x4 a1e = f32x4{0.f, 0.f, 0.f, 0.f};
        f32x4 a1o = f32x4{0.f, 0.f, 0.f, 0.f};

        // ---- h B-frags: ping-pong groups of 8, counted vmcnt(8) so the
        //      next group is always in flight while this one feeds MFMAs.
        //      Peak live h-regs = 64 VGPR (no spill; r9's hb[32] spilled).
        const bf16* hb_base = hin + (size_t)b * HD_ + quad * 8;
        i32x4 hbA[8], hbB[8];

        auto consume8 = [&](const i32x4* hbg, const int kkb) {
#pragma unroll
            for (int i = 0; i < 8; i += 2) {
                const int kk = kkb + i;
                const bf16x8 w0e = *reinterpret_cast<const bf16x8*>(wb + (size_t)kk * 1024);
                const bf16x8 w1e = *reinterpret_cast<const bf16x8*>(wb + (size_t)kk * 1024 + 512);
                const bf16x8 w0o = *reinterpret_cast<const bf16x8*>(wb + (size_t)(kk + 1) * 1024);
                const bf16x8 w1o = *reinterpret_cast<const bf16x8*>(wb + (size_t)(kk + 1) * 1024 + 512);
                a0e = __builtin_amdgcn_mfma_f32_16x16x32_bf16(w0e, as_bf16x8(hbg[i]), a0e, 0, 0, 0);
                a1e = __builtin_amdgcn_mfma_f32_16x16x32_bf16(w1e, as_bf16x8(hbg[i]), a1e, 0, 0, 0);
                a0o = __builtin_amdgcn_mfma_f32_16x16x32_bf16(w0o, as_bf16x8(hbg[i + 1]), a0o, 0, 0, 0);
                a1o = __builtin_amdgcn_mfma_f32_16x16x32_bf16(w1o, as_bf16x8(hbg[i + 1]), a1o, 0, 0, 0);
            }
        };

        issue8(hbA, hb_base);             // kk  0..7
        issue8(hbB, hb_base + 8 * 32);    // kk  8..15
        asm volatile("s_waitcnt vmcnt(8)" ::: "memory");
        __builtin_amdgcn_sched_barrier(0);
        consume8(hbA, 0);
        issue8(hbA, hb_base + 16 * 32);   // kk 16..23
        asm volatile("s_waitcnt vmcnt(8)" ::: "memory");
        __builtin_amdgcn_sched_barrier(0);
        consume8(hbB, 8);
        issue8(hbB, hb_base + 24 * 32);   // kk 24..31
        asm volatile("s_waitcnt vmcnt(8)" ::: "memory");
        __builtin_amdgcn_sched_barrier(0);
        consume8(hbA, 16);
        asm volatile("s_waitcnt vmcnt(0)" ::: "memory");
        __builtin_amdgcn_sched_barrier(0);
        consume8(hbB, 24);

        const f32x4 acc0 = a0e + a0o;
        const f32x4 acc1 = a1e + a1o;

        // ---- activations (own 8 lcols: acc0 -> lcol=quad*4+r, acc1 -> +16) ----
        float v0[4], v1[4];
#pragma unroll
        for (int r = 0; r < 4; ++r) {
            const float p0 = acc0[r] + (float)gx[r];
            const float p1 = acc1[r] + (float)gx[4 + r];
            v0[r] = sigmoid_fast(p0);                              // F or I
            v1[r] = (quad < 2) ? tanh_fast(p1) : sigmoid_fast(p1); // A or O
        }
        // ---- exchange with quad^2 partner (lane ^ 32) ----
        float u0[4], u1[4];
#pragma unroll
        for (int r = 0; r < 4; ++r) {
            u0[r] = __shfl_xor(v0[r], 32, 64);
            u1[r] = __shfl_xor(v1[r], 32, 64);
        }
        const int rsel = 2 * (quad >> 1);
        const float f0 = (quad < 2) ? v0[rsel]     : u0[rsel];
        const float i0 = (quad < 2) ? u0[rsel]     : v0[rsel];
        const float a0 = (quad < 2) ? v1[rsel]     : u1[rsel];
        const float o0 = (quad < 2) ? u1[rsel]     : v1[rsel];
        const float f1 = (quad < 2) ? v0[rsel + 1] : u0[rsel + 1];
        const float i1 = (quad < 2) ? u0[rsel + 1] : v0[rsel + 1];
        const float a1 = (quad < 2) ? v1[rsel + 1] : u1[rsel + 1];
        const float o1 = (quad < 2) ? u1[rsel + 1] : v1[rsel + 1];

        const float cn0 = f0 * c0 + i0 * a0;  c0 = cn0;
        const float cn1 = f1 * c1 + i1 * a1;  c1 = cn1;
        const float h0 = o0 * tanh_fast(cn0);
        const float h1 = o1 * tanh_fast(cn1);

        const int hidx = b * HD_ + blk * UPB + jl0;
        if (t < T_ - 1) {
            // publish h first: drain covers ONLY this one MALL store ack.
            const unsigned int packed =
                (unsigned int)bf16_bits(h0) | ((unsigned int)bf16_bits(h1) << 16);
            *reinterpret_cast<volatile unsigned int*>(hout + hidx) = packed;
            __asm__ __volatile__("s_waitcnt vmcnt(0)" ::: "memory");
            if (lane == 0)
                *reinterpret_cast<volatile int*>(flags + (w << 7) + blk) = t + 1;
            __asm__ __volatile__("" ::: "memory");
            // prefetch next step's gx now: a full step of latency to hide,
            // and it is never caught by a pre-flag drain.
            gx_next = *reinterpret_cast<const bf16x8*>(
                gates3 + (((size_t)(t + 1) * NBLK + blk) * 256 + tid) * 8);
        }
        // out stores off the inter-block critical path (after flag publish)
        *reinterpret_cast<float2*>(
            out + ((size_t)b * T_ + t) * HD_ + blk * UPB + jl0) =
            make_float2(h0, h1);
        if (t == T_ - 1) {
            *reinterpret_cast<float2*>(out + (size_t)M1_ * HD_ + hidx) =
                make_float2(h0, h1);
            *reinterpret_cast<float2*>(
                out + (size_t)M1_ * HD_ + B_ * HD_ + hidx) =
                make_float2(cn0, cn1);
        }
    }
}

// -------------------------------------------------------------- launcher ----
extern "C" void kernel_launch(void* const* d_in, const int* in_sizes, int n_in,
                              void* d_out, int out_size, void* d_ws, size_t ws_size,
                              hipStream_t stream) {
    const float* x  = (const float*)d_in[0];
    const float* Wi = (const float*)d_in[1];
    const float* bi = (const float*)d_in[2];
    const float* Wh = (const float*)d_in[3];
    const float* bh = (const float*)d_in[4];
    float* out = (float*)d_out;

    char* ws = (char*)d_ws;
    size_t off = 0;
    bf16* xb     = (bf16*)(ws + off); off += (size_t)M1_ * ID_ * 2;       // 16 MB
    bf16* wiT    = (bf16*)(ws + off); off += (size_t)NG_ * ID_ * 2;       // 4 MB
    bf16* whT    = (bf16*)(ws + off); off += (size_t)NG_ * HD_ * 2;       // 8 MB
    bf16* gates3 = (bf16*)(ws + off); off += (size_t)T_ * B_ * NG_ * 2;   // 128 MB
    bf16* hbuf   = (bf16*)(ws + off); off += (size_t)2 * B_ * HD_ * 2;    // 256 KB
    int* flags   = (int*)(ws + off);  off += (size_t)NBLK * 4 * 16 * 4;   // 32 KB

    prep_kernel<<<8192, 256, 0, stream>>>(x, Wi, Wh, xb, wiT, whT, hbuf, flags);
    gates_gemm_kernel<<<dim3(128, 32), 256, 0, stream>>>(xb, wiT, bi, bh, gates3);

    lstm_persistent_kernel<<<dim3(NBLK), dim3(256), 0, stream>>>(
        gates3, whT, hbuf, out, flags);
}

// Round 8
// 2149.807 us; speedup vs baseline: 1.5195x; 1.1915x over previous
//
#include <hip/hip_runtime.h>
#include <hip/hip_bf16.h>

// LSTM B=64, T=256, ID=512, HD=1024. Gates F,I,A,O.
// Round 12: sync-fabric decongestion. h-load mechanics are exonerated
// (r7 volatile / r8 LDS / r9 batched / r11 counted-vmcnt all ~8.5-10us/step).
// Remaining suspects, both fixed here:
//  (a) POLL CONGESTION: 512 waves x 8 cachelines polling MALL every ~760cy
//      ~ 13G req/s of pure poll traffic -- same order as total TCC request
//      throughput; taxes every critical MALL op. Fix: ONE flag per block
//      (producer: per-wave vmcnt(0) -> s_barrier -> wave0 stores flag);
//      consumer: ONLY wave 0 polls (64 lanes x dwordx2 over 128 contiguous
//      flags), waves 1-3 released by s_barrier; s_sleep(2) backoff.
//      Poll+flag MALL traffic / 4-8.
//  (b) PREV-STEP out-STORE ACK ON LOAD PATH: stores count in vmcnt; the
//      post-flag out store (r7 "optimization") becomes the oldest
//      outstanding op drained by next step's vmcnt(8). Fix: out stores
//      BEFORE the publish drain so their ack overlaps the h-store ack.
// Compute path identical to r11 (ping-pong issue8 "=&v", counted vmcnt(8),
// conflict-free LDS Wh, 4 MFMA chains, quad-exchange activations).

#define B_  64
#define T_  256
#define ID_ 512
#define HD_ 1024
#define NG_ 4096
#define M1_ (B_ * T_)
#define NBLK 128
#define UPB  8

typedef __bf16 bf16x8 __attribute__((ext_vector_type(8)));
typedef float  f32x4  __attribute__((ext_vector_type(4)));
typedef int    i32x4  __attribute__((ext_vector_type(4)));
typedef int    i32x2  __attribute__((ext_vector_type(2)));
typedef short  s16x4  __attribute__((ext_vector_type(4)));

using bf16 = __hip_bfloat16;

__device__ __forceinline__ float sigmoid_fast(float x) {
    return 1.0f / (1.0f + __expf(-x));
}
__device__ __forceinline__ float tanh_fast(float x) {
    return 1.0f - 2.0f / (__expf(2.0f * x) + 1.0f);
}
__device__ __forceinline__ unsigned short bf16_bits(float x) {
    union { bf16 h; unsigned short u; } cv;
    cv.h = __float2bfloat16(x);
    return cv.u;
}
__device__ __forceinline__ bf16x8 as_bf16x8(i32x4 v) {
    union { i32x4 i; bf16x8 h; } cv;
    cv.i = v;
    return cv.h;
}

// 8 coherent 16-B loads from one base (offsets 0..448 B), one asm block.
// "=&v" EARLY-CLOBBER is load-bearing: outputs must not alias the address
// pair (loads 2-8 read %8 after load 1's data can return).
__device__ __forceinline__ void issue8(i32x4* dst, const bf16* gbase) {
    asm volatile(
        "global_load_dwordx4 %0, %8, off sc0 sc1\n\t"
        "global_load_dwordx4 %1, %8, off offset:64 sc0 sc1\n\t"
        "global_load_dwordx4 %2, %8, off offset:128 sc0 sc1\n\t"
        "global_load_dwordx4 %3, %8, off offset:192 sc0 sc1\n\t"
        "global_load_dwordx4 %4, %8, off offset:256 sc0 sc1\n\t"
        "global_load_dwordx4 %5, %8, off offset:320 sc0 sc1\n\t"
        "global_load_dwordx4 %6, %8, off offset:384 sc0 sc1\n\t"
        "global_load_dwordx4 %7, %8, off offset:448 sc0 sc1"
        : "=&v"(dst[0]), "=&v"(dst[1]), "=&v"(dst[2]), "=&v"(dst[3]),
          "=&v"(dst[4]), "=&v"(dst[5]), "=&v"(dst[6]), "=&v"(dst[7])
        : "v"(gbase));
}

// ---------------------------------------------------------------- prep ----
__global__ __launch_bounds__(256) void prep_kernel(
    const float* __restrict__ x, const float* __restrict__ Wi,
    const float* __restrict__ Wh, bf16* __restrict__ xb,
    bf16* __restrict__ wiT, bf16* __restrict__ whT,
    bf16* __restrict__ hbuf, int* __restrict__ flags) {
    const int tid = blockIdx.x * 256 + threadIdx.x;  // [0, 2097152)

    if (tid < NBLK * 4 * 16) flags[tid] = 0;          // covers 128 block flags
    if (tid < (B_ * HD_) / 4)                         // h[-1] = 0 (buf0)
        *reinterpret_cast<s16x4*>(hbuf + (size_t)tid * 4) = s16x4{0, 0, 0, 0};

    const float4 v = reinterpret_cast<const float4*>(x)[tid];
    bf16 tmp[4] = { __float2bfloat16(v.x), __float2bfloat16(v.y),
                    __float2bfloat16(v.z), __float2bfloat16(v.w) };
    *reinterpret_cast<s16x4*>(xb + 4 * (size_t)tid) =
        *reinterpret_cast<s16x4*>(tmp);

    {   // WiT[n][k] = Wi[k][n]
        const int n = tid >> 9, k = tid & 511;
        wiT[tid] = __float2bfloat16(Wi[(size_t)k * NG_ + n]);
    }
    for (int e = 0; e < 2; ++e) {  // WhT[n][k] = Wh[k][n]
        const int idx = 2 * tid + e;
        const int n = idx >> 10, k = idx & 1023;
        whT[idx] = __float2bfloat16(Wh[(size_t)k * NG_ + n]);
    }
}

// ---------------------------------------------------- phase-1 gates GEMM ----
// gates3 layout: [t][blk][tid(256)][8] bf16, e = nt*4+r in step-MFMA acc order.
__global__ __launch_bounds__(256) void gates_gemm_kernel(
    const bf16* __restrict__ xb, const bf16* __restrict__ wiT,
    const float* __restrict__ bi, const float* __restrict__ bh,
    bf16* __restrict__ gates3) {
    __shared__ __align__(16) bf16 As[128 * 40];
    __shared__ __align__(16) bf16 Bs[128 * 40];
    const int tid  = threadIdx.x;
    const int lane = tid & 63, wave = tid >> 6;
    const int wm = wave >> 1, wn = wave & 1;
    const int l15 = lane & 15, quad = lane >> 4;
    const int row0 = blockIdx.x * 128, col0 = blockIdx.y * 128;

    f32x4 acc[4][4];
    for (int i = 0; i < 4; ++i)
        for (int j = 0; j < 4; ++j) acc[i][j] = f32x4{0.f, 0.f, 0.f, 0.f};

    for (int kt = 0; kt < ID_ / 32; ++kt) {
        const int k0 = kt * 32;
        for (int L = tid; L < 512; L += 256) {
            const int r = L >> 2, s = L & 3;
            *reinterpret_cast<i32x4*>(&As[r * 40 + s * 8]) =
                *reinterpret_cast<const i32x4*>(xb + (size_t)(row0 + r) * ID_ + k0 + s * 8);
            *reinterpret_cast<i32x4*>(&Bs[r * 40 + s * 8]) =
                *reinterpret_cast<const i32x4*>(wiT + (size_t)(col0 + r) * ID_ + k0 + s * 8);
        }
        __syncthreads();
        bf16x8 af[4], bfv[4];
        for (int mt = 0; mt < 4; ++mt)
            af[mt] = *reinterpret_cast<const bf16x8*>(
                &As[(wm * 64 + mt * 16 + l15) * 40 + quad * 8]);
        for (int nt = 0; nt < 4; ++nt)
            bfv[nt] = *reinterpret_cast<const bf16x8*>(
                &Bs[(wn * 64 + nt * 16 + l15) * 40 + quad * 8]);
        for (int mt = 0; mt < 4; ++mt)
            for (int nt = 0; nt < 4; ++nt)
                acc[mt][nt] = __builtin_amdgcn_mfma_f32_16x16x32_bf16(
                    af[mt], bfv[nt], acc[mt][nt], 0, 0, 0);
        __syncthreads();
    }
    // epilogue: +(bi+bh), store to gates3 in persistent-kernel acc order
    for (int mt = 0; mt < 4; ++mt) {
        for (int nt = 0; nt < 4; ++nt) {
            const int cg = col0 + wn * 64 + nt * 16 + l15;
            const int g = cg >> 10, u = cg & 1023;
            const int blk = u >> 3, jl = u & 7;
            const int lcol = g * 8 + jl;               // m-index in step MFMA
            const int nt2 = lcol >> 4, q2 = (lcol >> 2) & 3, r2 = lcol & 3;
            const int e = nt2 * 4 + r2;
            const float bias = bi[cg] + bh[cg];
            for (int r = 0; r < 4; ++r) {
                const int rg = row0 + wm * 64 + mt * 16 + quad * 4 + r;
                const int b = rg >> 8, t = rg & 255;   // row = b*T + t
                const int tid2 = (b >> 4) * 64 + q2 * 16 + (b & 15);
                gates3[(((size_t)t * NBLK + blk) * 256 + tid2) * 8 + e] =
                    __float2bfloat16(acc[mt][nt][r] + bias);
            }
        }
    }
}

// ------------------------------------------------- persistent LSTM steps ----
// LDS Wh tile layout: byte = kk*2048 + sel*1024 + lane*16  (kk=0..31, sel=0/1
// for the two m-halves, lane=0..63). Lane i always reads byte 16*i within a
// 1024-B slab -> contiguous conflict-free b128 pattern by construction.
__global__ __launch_bounds__(256, 1) void lstm_persistent_kernel(
    const bf16* __restrict__ gates3, const bf16* __restrict__ whT,
    bf16* __restrict__ hbuf, float* __restrict__ out, int* __restrict__ flags) {
    __shared__ __align__(16) bf16 whs[32 * 2 * 64 * 8];   // 64 KB
    const int tid  = threadIdx.x;
    const int lane = tid & 63, w = tid >> 6;
    const int l15 = lane & 15, quad = lane >> 4;
    const int blk = blockIdx.x;                 // hidden units [blk*8, blk*8+8)

    // ---- stage Wh A-tile into LDS (once), linear-in-tid writes ----
    for (int c = tid; c < 4096; c += 256) {
        const int kk = c >> 7, sel = (c >> 6) & 1, ln = c & 63;
        const int m = sel * 16 + (ln & 15);
        const size_t wrow = (size_t)((m >> 3) * HD_ + blk * UPB + (m & 7));
        const int col = (ln >> 4) * 8 + kk * 32;
        *reinterpret_cast<i32x4*>(whs + (size_t)c * 8) =
            *reinterpret_cast<const i32x4*>(whT + wrow * HD_ + col);
    }
    __syncthreads();

    const bf16* wb = whs + (size_t)lane * 8;   // + kk*1024 (+512 for sel=1)

    // cell-update map (after shfl_xor(32) pairing quad<->quad^2):
    // thread covers (b = w*16+l15, units jl0, jl0+1)
    const int jl0 = 4 * (quad & 1) + 2 * (quad >> 1);
    const int b = w * 16 + l15;
    float c0 = 0.f, c1 = 0.f;

    // block-level flags[0..127], contiguous. Wave 0 polls blocks 2*lane,
    // 2*lane+1 with one dwordx2 (8 cachelines per polling wave, 128 polling
    // waves chip-wide -- 1/4 of the old per-wave-flag scheme's traffic).
    const int* pollp = flags + (lane << 1);

    // gx double-buffer: prefetch step 0 now; step t+1 is issued after the
    // publish barrier so the publish vmcnt(0) never waits on an HBM load.
    bf16x8 gx_next = *reinterpret_cast<const bf16x8*>(
        gates3 + ((size_t)blk * 256 + tid) * 8);

    for (int t = 0; t < T_; ++t) {
        const bf16* hin  = hbuf + (size_t)(t & 1) * (B_ * HD_);
        bf16*       hout = hbuf + (size_t)((t + 1) & 1) * (B_ * HD_);
        const bf16x8 gx = gx_next;

        // wait until all 128 blocks published h[t-1]: wave 0 polls, then
        // releases waves 1-3 via s_barrier.
        if (t > 0) {
            if (w == 0) {
                for (;;) {
                    i32x2 f = *reinterpret_cast<const volatile i32x2*>(pollp);
                    if (f.x >= t && f.y >= t) break;
                    __builtin_amdgcn_s_sleep(2);
                }
            }
            asm volatile("s_barrier" ::: "memory");
        }

        f32x4 a0e = f32x4{0.f, 0.f, 0.f, 0.f};
        f32x4 a0o = f32x4{0.f, 0.f, 0.f, 0.f};
        f32x4 a1e = f32x4{0.f, 0.f, 0.f, 0.f};
        f32x4 a1o = f32x4{0.f, 0.f, 0.f, 0.f};

        // ---- h B-frags: ping-pong groups of 8, counted vmcnt(8) so the
        //      next group is always in flight while this one feeds MFMAs.
        const bf16* hb_base = hin + (size_t)b * HD_ + quad * 8;
        i32x4 hbA[8], hbB[8];

        auto consume8 = [&](const i32x4* hbg, const int kkb) {
#pragma unroll
            for (int i = 0; i < 8; i += 2) {
                const int kk = kkb + i;
                const bf16x8 w0e = *reinterpret_cast<const bf16x8*>(wb + (size_t)kk * 1024);
                const bf16x8 w1e = *reinterpret_cast<const bf16x8*>(wb + (size_t)kk * 1024 + 512);
                const bf16x8 w0o = *reinterpret_cast<const bf16x8*>(wb + (size_t)(kk + 1) * 1024);
                const bf16x8 w1o = *reinterpret_cast<const bf16x8*>(wb + (size_t)(kk + 1) * 1024 + 512);
                a0e = __builtin_amdgcn_mfma_f32_16x16x32_bf16(w0e, as_bf16x8(hbg[i]), a0e, 0, 0, 0);
                a1e = __builtin_amdgcn_mfma_f32_16x16x32_bf16(w1e, as_bf16x8(hbg[i]), a1e, 0, 0, 0);
                a0o = __builtin_amdgcn_mfma_f32_16x16x32_bf16(w0o, as_bf16x8(hbg[i + 1]), a0o, 0, 0, 0);
                a1o = __builtin_amdgcn_mfma_f32_16x16x32_bf16(w1o, as_bf16x8(hbg[i + 1]), a1o, 0, 0, 0);
            }
        };

        issue8(hbA, hb_base);             // kk  0..7
        issue8(hbB, hb_base + 8 * 32);    // kk  8..15
        asm volatile("s_waitcnt vmcnt(8)" ::: "memory");
        __builtin_amdgcn_sched_barrier(0);
        consume8(hbA, 0);
        issue8(hbA, hb_base + 16 * 32);   // kk 16..23
        asm volatile("s_waitcnt vmcnt(8)" ::: "memory");
        __builtin_amdgcn_sched_barrier(0);
        consume8(hbB, 8);
        issue8(hbB, hb_base + 24 * 32);   // kk 24..31
        asm volatile("s_waitcnt vmcnt(8)" ::: "memory");
        __builtin_amdgcn_sched_barrier(0);
        consume8(hbA, 16);
        asm volatile("s_waitcnt vmcnt(0)" ::: "memory");
        __builtin_amdgcn_sched_barrier(0);
        consume8(hbB, 24);

        const f32x4 acc0 = a0e + a0o;
        const f32x4 acc1 = a1e + a1o;

        // ---- activations (own 8 lcols: acc0 -> lcol=quad*4+r, acc1 -> +16) ----
        float v0[4], v1[4];
#pragma unroll
        for (int r = 0; r < 4; ++r) {
            const float p0 = acc0[r] + (float)gx[r];
            const float p1 = acc1[r] + (float)gx[4 + r];
            v0[r] = sigmoid_fast(p0);                              // F or I
            v1[r] = (quad < 2) ? tanh_fast(p1) : sigmoid_fast(p1); // A or O
        }
        // ---- exchange with quad^2 partner (lane ^ 32) ----
        float u0[4], u1[4];
#pragma unroll
        for (int r = 0; r < 4; ++r) {
            u0[r] = __shfl_xor(v0[r], 32, 64);
            u1[r] = __shfl_xor(v1[r], 32, 64);
        }
        const int rsel = 2 * (quad >> 1);
        const float f0 = (quad < 2) ? v0[rsel]     : u0[rsel];
        const float i0 = (quad < 2) ? u0[rsel]     : v0[rsel];
        const float a0 = (quad < 2) ? v1[rsel]     : u1[rsel];
        const float o0 = (quad < 2) ? u1[rsel]     : v1[rsel];
        const float f1 = (quad < 2) ? v0[rsel + 1] : u0[rsel + 1];
        const float i1 = (quad < 2) ? u0[rsel + 1] : v0[rsel + 1];
        const float a1 = (quad < 2) ? v1[rsel + 1] : u1[rsel + 1];
        const float o1 = (quad < 2) ? u1[rsel + 1] : v1[rsel + 1];

        const float cn0 = f0 * c0 + i0 * a0;  c0 = cn0;
        const float cn1 = f1 * c1 + i1 * a1;  c1 = cn1;
        const float h0 = o0 * tanh_fast(cn0);
        const float h1 = o1 * tanh_fast(cn1);

        const int hidx = b * HD_ + blk * UPB + jl0;
        // out stores FIRST: their HBM acks drain inside the publish
        // vmcnt(0) (overlapped with the h MALL ack) instead of stalling
        // next step's vmcnt(8) as the oldest outstanding op.
        *reinterpret_cast<float2*>(
            out + ((size_t)b * T_ + t) * HD_ + blk * UPB + jl0) =
            make_float2(h0, h1);
        if (t == T_ - 1) {
            *reinterpret_cast<float2*>(out + (size_t)M1_ * HD_ + hidx) =
                make_float2(h0, h1);
            *reinterpret_cast<float2*>(
                out + (size_t)M1_ * HD_ + B_ * HD_ + hidx) =
                make_float2(cn0, cn1);
        }
        if (t < T_ - 1) {
            const unsigned int packed =
                (unsigned int)bf16_bits(h0) | ((unsigned int)bf16_bits(h1) << 16);
            *reinterpret_cast<volatile unsigned int*>(hout + hidx) = packed;
            // drain own h (MALL) + out (HBM) acks, then block-wide barrier,
            // then ONE flag store for the whole block.
            __asm__ __volatile__("s_waitcnt vmcnt(0)" ::: "memory");
            asm volatile("s_barrier" ::: "memory");
            if (tid == 0)
                *reinterpret_cast<volatile int*>(flags + blk) = t + 1;
            __asm__ __volatile__("" ::: "memory");
            // prefetch next step's gx: a full step of latency to hide.
            gx_next = *reinterpret_cast<const bf16x8*>(
                gates3 + (((size_t)(t + 1) * NBLK + blk) * 256 + tid) * 8);
        }
    }
}

// -------------------------------------------------------------- launcher ----
extern "C" void kernel_launch(void* const* d_in, const int* in_sizes, int n_in,
                              void* d_out, int out_size, void* d_ws, size_t ws_size,
                              hipStream_t stream) {
    const float* x  = (const float*)d_in[0];
    const float* Wi = (const float*)d_in[1];
    const float* bi = (const float*)d_in[2];
    const float* Wh = (const float*)d_in[3];
    const float* bh = (const float*)d_in[4];
    float* out = (float*)d_out;

    char* ws = (char*)d_ws;
    size_t off = 0;
    bf16* xb     = (bf16*)(ws + off); off += (size_t)M1_ * ID_ * 2;       // 16 MB
    bf16* wiT    = (bf16*)(ws + off); off += (size_t)NG_ * ID_ * 2;       // 4 MB
    bf16* whT    = (bf16*)(ws + off); off += (size_t)NG_ * HD_ * 2;       // 8 MB
    bf16* gates3 = (bf16*)(ws + off); off += (size_t)T_ * B_ * NG_ * 2;   // 128 MB
    bf16* hbuf   = (bf16*)(ws + off); off += (size_t)2 * B_ * HD_ * 2;    // 256 KB
    int* flags   = (int*)(ws + off);  off += (size_t)NBLK * 4 * 16 * 4;   // 32 KB

    prep_kernel<<<8192, 256, 0, stream>>>(x, Wi, Wh, xb, wiT, whT, hbuf, flags);
    gates_gemm_kernel<<<dim3(128, 32), 256, 0, stream>>>(xb, wiT, bi, bh, gates3);

    lstm_persistent_kernel<<<dim3(NBLK), dim3(256), 0, stream>>>(
        gates3, whT, hbuf, out, flags);
}

// Round 9
// 2049.934 us; speedup vs baseline: 1.5936x; 1.0487x over previous
//
#include <hip/hip_runtime.h>
#include <hip/hip_bf16.h>

// LSTM B=64, T=256, ID=512, HD=1024. Gates F,I,A,O.
// Round 13: halve the MALL all-to-all. r12 confirmed the congestion theory
// (poll-traffic /4 -> -19%). Remaining dominant term: 128 blocks x 128 KB
// coherent h reads = 16 MB/step burst through MALL (~5us at ~3TB/s eff).
//  (1) NBLK 128->64, UPB 8->16: per-step coherent read volume 16->8 MB,
//      sync participants 128->64.
//  (2) Free bonus: with 16 units/gate-tile, each MFMA sel-tile is exactly
//      one gate -> every thread's 4 accs hold F,I,A,O for the SAME
//      (unit,batch): quad shfl_xor exchange + divergent tanh/sigmoid
//      selection deleted. h publish = one packed dwordx2; out = float4.
//  (3) Wh LDS tile 64 rows x 1024 k = 128 KB (fits 160 KB, 1 block/CU),
//      same conflict-free layout: elem = kk*2048 + sel*512 + lane*8.
//  (4) gates3 layout now [t][blk][tid][16], e = gate*4 + (unit&3); GEMM
//      epilogue mapping rewritten to match.
// Pipeline mechanics unchanged from r12 (issue8 "=&v", counted vmcnt(8),
// block flag after drain+barrier, wave0-polls, gx prefetched post-publish).

#define B_  64
#define T_  256
#define ID_ 512
#define HD_ 1024
#define NG_ 4096
#define M1_ (B_ * T_)
#define NBLK 64
#define UPB  16

typedef __bf16 bf16x8 __attribute__((ext_vector_type(8)));
typedef float  f32x4  __attribute__((ext_vector_type(4)));
typedef int    i32x4  __attribute__((ext_vector_type(4)));
typedef short  s16x4  __attribute__((ext_vector_type(4)));

using bf16 = __hip_bfloat16;

__device__ __forceinline__ float sigmoid_fast(float x) {
    return 1.0f / (1.0f + __expf(-x));
}
__device__ __forceinline__ float tanh_fast(float x) {
    return 1.0f - 2.0f / (__expf(2.0f * x) + 1.0f);
}
__device__ __forceinline__ unsigned short bf16_bits(float x) {
    union { bf16 h; unsigned short u; } cv;
    cv.h = __float2bfloat16(x);
    return cv.u;
}
__device__ __forceinline__ bf16x8 as_bf16x8(i32x4 v) {
    union { i32x4 i; bf16x8 h; } cv;
    cv.i = v;
    return cv.h;
}

// 8 coherent 16-B loads from one base (offsets 0..448 B), one asm block.
// "=&v" EARLY-CLOBBER is load-bearing: outputs must not alias the address
// pair (loads 2-8 read %8 after load 1's data can return).
__device__ __forceinline__ void issue8(i32x4* dst, const bf16* gbase) {
    asm volatile(
        "global_load_dwordx4 %0, %8, off sc0 sc1\n\t"
        "global_load_dwordx4 %1, %8, off offset:64 sc0 sc1\n\t"
        "global_load_dwordx4 %2, %8, off offset:128 sc0 sc1\n\t"
        "global_load_dwordx4 %3, %8, off offset:192 sc0 sc1\n\t"
        "global_load_dwordx4 %4, %8, off offset:256 sc0 sc1\n\t"
        "global_load_dwordx4 %5, %8, off offset:320 sc0 sc1\n\t"
        "global_load_dwordx4 %6, %8, off offset:384 sc0 sc1\n\t"
        "global_load_dwordx4 %7, %8, off offset:448 sc0 sc1"
        : "=&v"(dst[0]), "=&v"(dst[1]), "=&v"(dst[2]), "=&v"(dst[3]),
          "=&v"(dst[4]), "=&v"(dst[5]), "=&v"(dst[6]), "=&v"(dst[7])
        : "v"(gbase));
}

// ---------------------------------------------------------------- prep ----
__global__ __launch_bounds__(256) void prep_kernel(
    const float* __restrict__ x, const float* __restrict__ Wi,
    const float* __restrict__ Wh, bf16* __restrict__ xb,
    bf16* __restrict__ wiT, bf16* __restrict__ whT,
    bf16* __restrict__ hbuf, int* __restrict__ flags) {
    const int tid = blockIdx.x * 256 + threadIdx.x;  // [0, 2097152)

    if (tid < NBLK * 4 * 16) flags[tid] = 0;          // covers 64 block flags
    if (tid < (B_ * HD_) / 4)                         // h[-1] = 0 (buf0)
        *reinterpret_cast<s16x4*>(hbuf + (size_t)tid * 4) = s16x4{0, 0, 0, 0};

    const float4 v = reinterpret_cast<const float4*>(x)[tid];
    bf16 tmp[4] = { __float2bfloat16(v.x), __float2bfloat16(v.y),
                    __float2bfloat16(v.z), __float2bfloat16(v.w) };
    *reinterpret_cast<s16x4*>(xb + 4 * (size_t)tid) =
        *reinterpret_cast<s16x4*>(tmp);

    {   // WiT[n][k] = Wi[k][n]
        const int n = tid >> 9, k = tid & 511;
        wiT[tid] = __float2bfloat16(Wi[(size_t)k * NG_ + n]);
    }
    for (int e = 0; e < 2; ++e) {  // WhT[n][k] = Wh[k][n]
        const int idx = 2 * tid + e;
        const int n = idx >> 10, k = idx & 1023;
        whT[idx] = __float2bfloat16(Wh[(size_t)k * NG_ + n]);
    }
}

// ---------------------------------------------------- phase-1 gates GEMM ----
// gates3 layout: [t][blk(64)][tid(256)][16] bf16, e = gate*4 + (unit&3),
// tid2 = (b>>4)*64 + (unit>>2)*16 + (b&15)  -- step-MFMA acc order (UPB=16).
__global__ __launch_bounds__(256) void gates_gemm_kernel(
    const bf16* __restrict__ xb, const bf16* __restrict__ wiT,
    const float* __restrict__ bi, const float* __restrict__ bh,
    bf16* __restrict__ gates3) {
    __shared__ __align__(16) bf16 As[128 * 40];
    __shared__ __align__(16) bf16 Bs[128 * 40];
    const int tid  = threadIdx.x;
    const int lane = tid & 63, wave = tid >> 6;
    const int wm = wave >> 1, wn = wave & 1;
    const int l15 = lane & 15, quad = lane >> 4;
    const int row0 = blockIdx.x * 128, col0 = blockIdx.y * 128;

    f32x4 acc[4][4];
    for (int i = 0; i < 4; ++i)
        for (int j = 0; j < 4; ++j) acc[i][j] = f32x4{0.f, 0.f, 0.f, 0.f};

    for (int kt = 0; kt < ID_ / 32; ++kt) {
        const int k0 = kt * 32;
        for (int L = tid; L < 512; L += 256) {
            const int r = L >> 2, s = L & 3;
            *reinterpret_cast<i32x4*>(&As[r * 40 + s * 8]) =
                *reinterpret_cast<const i32x4*>(xb + (size_t)(row0 + r) * ID_ + k0 + s * 8);
            *reinterpret_cast<i32x4*>(&Bs[r * 40 + s * 8]) =
                *reinterpret_cast<const i32x4*>(wiT + (size_t)(col0 + r) * ID_ + k0 + s * 8);
        }
        __syncthreads();
        bf16x8 af[4], bfv[4];
        for (int mt = 0; mt < 4; ++mt)
            af[mt] = *reinterpret_cast<const bf16x8*>(
                &As[(wm * 64 + mt * 16 + l15) * 40 + quad * 8]);
        for (int nt = 0; nt < 4; ++nt)
            bfv[nt] = *reinterpret_cast<const bf16x8*>(
                &Bs[(wn * 64 + nt * 16 + l15) * 40 + quad * 8]);
        for (int mt = 0; mt < 4; ++mt)
            for (int nt = 0; nt < 4; ++nt)
                acc[mt][nt] = __builtin_amdgcn_mfma_f32_16x16x32_bf16(
                    af[mt], bfv[nt], acc[mt][nt], 0, 0, 0);
        __syncthreads();
    }
    // epilogue: +(bi+bh), store to gates3 in persistent-kernel acc order
    for (int mt = 0; mt < 4; ++mt) {
        for (int nt = 0; nt < 4; ++nt) {
            const int cg = col0 + wn * 64 + nt * 16 + l15;
            const int g = cg >> 10, u = cg & 1023;      // gate, hidden unit
            const int blk = u >> 4, ul = u & 15;
            const int q2 = ul >> 2, r2 = ul & 3;
            const int e = g * 4 + r2;
            const float bias = bi[cg] + bh[cg];
            for (int r = 0; r < 4; ++r) {
                const int rg = row0 + wm * 64 + mt * 16 + quad * 4 + r;
                const int b = rg >> 8, t = rg & 255;    // row = b*T + t
                const int tid2 = (b >> 4) * 64 + q2 * 16 + (b & 15);
                gates3[(((size_t)t * NBLK + blk) * 256 + tid2) * 16 + e] =
                    __float2bfloat16(acc[mt][nt][r] + bias);
            }
        }
    }
}

// ------------------------------------------------- persistent LSTM steps ----
// LDS Wh tile: 64 m-rows (4 gates x 16 units) x 1024 k, 128 KB.
// Element layout: kk*2048 + sel*512 + lane*8 (sel = gate). Lane i reads
// element 8*i of its (kk,sel) slab -> contiguous conflict-free b128.
__global__ __launch_bounds__(256, 1) void lstm_persistent_kernel(
    const bf16* __restrict__ gates3, const bf16* __restrict__ whT,
    bf16* __restrict__ hbuf, float* __restrict__ out, int* __restrict__ flags) {
    __shared__ __align__(16) bf16 whs[32 * 4 * 64 * 8];   // 128 KB
    const int tid  = threadIdx.x;
    const int lane = tid & 63, w = tid >> 6;
    const int l15 = lane & 15, quad = lane >> 4;
    const int blk = blockIdx.x;                 // units [blk*16, blk*16+16)

    // ---- stage Wh A-tile into LDS (once), linear-in-tid 16B writes ----
    for (int c = tid; c < 8192; c += 256) {
        const int kk = c >> 8, sel = (c >> 6) & 3, ln = c & 63;
        const size_t wrow = (size_t)(sel * HD_ + blk * UPB + (ln & 15));
        const int col = (ln >> 4) * 8 + kk * 32;
        *reinterpret_cast<i32x4*>(whs + (size_t)c * 8) =
            *reinterpret_cast<const i32x4*>(whT + wrow * HD_ + col);
    }
    __syncthreads();

    const bf16* wb = whs + (size_t)lane * 8;    // + kk*2048 + sel*512

    // thread owns (batch b = w*16+l15, units quad*4 .. quad*4+3)
    const int b = w * 16 + l15;
    float cs[4] = {0.f, 0.f, 0.f, 0.f};

    // block flags[0..63]: wave 0, lane i polls flags[i]; waves 1-3 released
    // by s_barrier. Producer: drain -> s_barrier -> tid0 stores flags[blk].
    const volatile int* pf = (const volatile int*)(flags + lane);

    // gx double-buffer (2 x bf16x8 = 16 gates: F r0-3, I r0-3 | A, O)
    size_t gb0 = ((size_t)blk * 256 + tid) * 16;
    bf16x8 gxa_n = *reinterpret_cast<const bf16x8*>(gates3 + gb0);
    bf16x8 gxb_n = *reinterpret_cast<const bf16x8*>(gates3 + gb0 + 8);

    for (int t = 0; t < T_; ++t) {
        const bf16* hin  = hbuf + (size_t)(t & 1) * (B_ * HD_);
        bf16*       hout = hbuf + (size_t)((t + 1) & 1) * (B_ * HD_);
        const bf16x8 gxa = gxa_n, gxb = gxb_n;

        if (t > 0) {
            if (w == 0) {
                while (*pf < t) __builtin_amdgcn_s_sleep(2);
            }
            asm volatile("s_barrier" ::: "memory");
        }

        f32x4 aFe{0.f,0.f,0.f,0.f}, aFo{0.f,0.f,0.f,0.f};
        f32x4 aIe{0.f,0.f,0.f,0.f}, aIo{0.f,0.f,0.f,0.f};
        f32x4 aAe{0.f,0.f,0.f,0.f}, aAo{0.f,0.f,0.f,0.f};
        f32x4 aOe{0.f,0.f,0.f,0.f}, aOo{0.f,0.f,0.f,0.f};

        // ---- h B-frags: ping-pong groups of 8, counted vmcnt(8) ----
        const bf16* hb_base = hin + (size_t)b * HD_ + quad * 8;
        i32x4 hbA[8], hbB[8];

        auto consume8 = [&](const i32x4* hbg, const int kkb) {
#pragma unroll
            for (int i = 0; i < 8; i += 2) {
                const int kk = kkb + i;
                const bf16* f0 = wb + (size_t)kk * 2048;
                const bf16* f1 = f0 + 2048;
                const bf16x8 he = as_bf16x8(hbg[i]);
                const bf16x8 ho = as_bf16x8(hbg[i + 1]);
                aFe = __builtin_amdgcn_mfma_f32_16x16x32_bf16(
                    *reinterpret_cast<const bf16x8*>(f0),        he, aFe, 0, 0, 0);
                aIe = __builtin_amdgcn_mfma_f32_16x16x32_bf16(
                    *reinterpret_cast<const bf16x8*>(f0 + 512),  he, aIe, 0, 0, 0);
                aAe = __builtin_amdgcn_mfma_f32_16x16x32_bf16(
                    *reinterpret_cast<const bf16x8*>(f0 + 1024), he, aAe, 0, 0, 0);
                aOe = __builtin_amdgcn_mfma_f32_16x16x32_bf16(
                    *reinterpret_cast<const bf16x8*>(f0 + 1536), he, aOe, 0, 0, 0);
                aFo = __builtin_amdgcn_mfma_f32_16x16x32_bf16(
                    *reinterpret_cast<const bf16x8*>(f1),        ho, aFo, 0, 0, 0);
                aIo = __builtin_amdgcn_mfma_f32_16x16x32_bf16(
                    *reinterpret_cast<const bf16x8*>(f1 + 512),  ho, aIo, 0, 0, 0);
                aAo = __builtin_amdgcn_mfma_f32_16x16x32_bf16(
                    *reinterpret_cast<const bf16x8*>(f1 + 1024), ho, aAo, 0, 0, 0);
                aOo = __builtin_amdgcn_mfma_f32_16x16x32_bf16(
                    *reinterpret_cast<const bf16x8*>(f1 + 1536), ho, aOo, 0, 0, 0);
            }
        };

        issue8(hbA, hb_base);             // kk  0..7
        issue8(hbB, hb_base + 8 * 32);    // kk  8..15
        asm volatile("s_waitcnt vmcnt(8)" ::: "memory");
        __builtin_amdgcn_sched_barrier(0);
        consume8(hbA, 0);
        issue8(hbA, hb_base + 16 * 32);   // kk 16..23
        asm volatile("s_waitcnt vmcnt(8)" ::: "memory");
        __builtin_amdgcn_sched_barrier(0);
        consume8(hbB, 8);
        issue8(hbB, hb_base + 24 * 32);   // kk 24..31
        asm volatile("s_waitcnt vmcnt(8)" ::: "memory");
        __builtin_amdgcn_sched_barrier(0);
        consume8(hbA, 16);
        asm volatile("s_waitcnt vmcnt(0)" ::: "memory");
        __builtin_amdgcn_sched_barrier(0);
        consume8(hbB, 24);

        // ---- activations: all 4 gates for (unit quad*4+r, batch b) are
        //      LOCAL (sel-tile == gate) -> no cross-lane exchange at all.
        const f32x4 accF = aFe + aFo;
        const f32x4 accI = aIe + aIo;
        const f32x4 accA = aAe + aAo;
        const f32x4 accO = aOe + aOo;
        float hs[4];
#pragma unroll
        for (int r = 0; r < 4; ++r) {
            const float fv = sigmoid_fast(accF[r] + (float)gxa[r]);
            const float iv = sigmoid_fast(accI[r] + (float)gxa[4 + r]);
            const float av = tanh_fast   (accA[r] + (float)gxb[r]);
            const float ov = sigmoid_fast(accO[r] + (float)gxb[4 + r]);
            cs[r] = fv * cs[r] + iv * av;
            hs[r] = ov * tanh_fast(cs[r]);
        }

        const int hidx = b * HD_ + blk * UPB + quad * 4;
        // out stores FIRST: acks drain inside the publish vmcnt(0),
        // overlapped with the h MALL ack (r12 lesson).
        *reinterpret_cast<float4*>(
            out + ((size_t)b * T_ + t) * HD_ + blk * UPB + quad * 4) =
            make_float4(hs[0], hs[1], hs[2], hs[3]);
        if (t == T_ - 1) {
            *reinterpret_cast<float4*>(out + (size_t)M1_ * HD_ + hidx) =
                make_float4(hs[0], hs[1], hs[2], hs[3]);
            *reinterpret_cast<float4*>(
                out + (size_t)M1_ * HD_ + B_ * HD_ + hidx) =
                make_float4(cs[0], cs[1], cs[2], cs[3]);
        }
        if (t < T_ - 1) {
            const unsigned long long hp =
                (unsigned long long)bf16_bits(hs[0]) |
                ((unsigned long long)bf16_bits(hs[1]) << 16) |
                ((unsigned long long)bf16_bits(hs[2]) << 32) |
                ((unsigned long long)bf16_bits(hs[3]) << 48);
            *reinterpret_cast<volatile unsigned long long*>(hout + hidx) = hp;
            // drain own h (MALL) + out acks, block barrier, ONE flag store.
            __asm__ __volatile__("s_waitcnt vmcnt(0)" ::: "memory");
            asm volatile("s_barrier" ::: "memory");
            if (tid == 0)
                *reinterpret_cast<volatile int*>(flags + blk) = t + 1;
            __asm__ __volatile__("" ::: "memory");
            // prefetch next step's gx: a full step of latency to hide.
            const size_t gb = (((size_t)(t + 1) * NBLK + blk) * 256 + tid) * 16;
            gxa_n = *reinterpret_cast<const bf16x8*>(gates3 + gb);
            gxb_n = *reinterpret_cast<const bf16x8*>(gates3 + gb + 8);
        }
    }
}

// -------------------------------------------------------------- launcher ----
extern "C" void kernel_launch(void* const* d_in, const int* in_sizes, int n_in,
                              void* d_out, int out_size, void* d_ws, size_t ws_size,
                              hipStream_t stream) {
    const float* x  = (const float*)d_in[0];
    const float* Wi = (const float*)d_in[1];
    const float* bi = (const float*)d_in[2];
    const float* Wh = (const float*)d_in[3];
    const float* bh = (const float*)d_in[4];
    float* out = (float*)d_out;

    char* ws = (char*)d_ws;
    size_t off = 0;
    bf16* xb     = (bf16*)(ws + off); off += (size_t)M1_ * ID_ * 2;       // 16 MB
    bf16* wiT    = (bf16*)(ws + off); off += (size_t)NG_ * ID_ * 2;       // 4 MB
    bf16* whT    = (bf16*)(ws + off); off += (size_t)NG_ * HD_ * 2;       // 8 MB
    bf16* gates3 = (bf16*)(ws + off); off += (size_t)T_ * B_ * NG_ * 2;   // 128 MB
    bf16* hbuf   = (bf16*)(ws + off); off += (size_t)2 * B_ * HD_ * 2;    // 256 KB
    int* flags   = (int*)(ws + off);  off += (size_t)NBLK * 4 * 16 * 4;   // 16 KB

    prep_kernel<<<8192, 256, 0, stream>>>(x, Wi, Wh, xb, wiT, whT, hbuf, flags);
    gates_gemm_kernel<<<dim3(128, 32), 256, 0, stream>>>(xb, wiT, bi, bh, gates3);

    lstm_persistent_kernel<<<dim3(NBLK), dim3(256), 0, stream>>>(
        gates3, whT, hbuf, out, flags);
}